// Round 4
// baseline (128.171 us; speedup 1.0000x reference)
//
#include <hip/hip_runtime.h>
#include <hip/hip_bf16.h>

// feature [B=128, E=64, D=128] fp32 -> N = 8192 rows of dim 128.
// loss = mean_r( log(den_r) - log(pos_r) ),
//   den_r = sum_c exp(10*<f_r,f_c>), pos_r = sum over c in r's 64-row block.
#define N_ROWS 8192
#define DIM    128
#define CPS    8     // 64-col steps per block
#define EXPTEN 22026.465794806718f  // exp(10.0)
// Xb = normalize(f) * SCALE, SCALE^2 = 10*log2(e); then exp2(dot) = exp(10*<f,f>)
#define SCALE  3.7982826f

typedef __attribute__((ext_vector_type(8))) short short8;   // 8 bf16 = 4 VGPRs
typedef __attribute__((ext_vector_type(4))) float floatx4;  // MFMA C/D

#define EXP2F(x) __builtin_amdgcn_exp2f(x)

// async global->LDS DMA, 16B per lane; LDS dest = wave-uniform base + lane*16
#define GLOAD_LDS(g, l)                                                        \
    __builtin_amdgcn_global_load_lds(                                          \
        (const __attribute__((address_space(1))) void*)(g),                    \
        (__attribute__((address_space(3))) void*)(l), 16, 0, 0)

// ---- Kernel 1: L2-normalize rows, scale, cast to bf16; zero pos/den ----
__global__ void norm_kernel(const float* __restrict__ F, __hip_bfloat16* __restrict__ Xb,
                            float* __restrict__ pos, float* __restrict__ den) {
    int lane = threadIdx.x & 63;
    int wave = threadIdx.x >> 6;
    int row  = blockIdx.x * 4 + wave;           // 2048 blocks x 4 waves = 8192 rows
    const float2 v = *(const float2*)(F + (size_t)row * DIM + lane * 2);
    float ss = v.x * v.x + v.y * v.y;
    #pragma unroll
    for (int m = 1; m < 64; m <<= 1) ss += __shfl_xor(ss, m);
    float inv = rsqrtf(ss) * SCALE;
    __hip_bfloat162 o;
    o.x = __float2bfloat16(v.x * inv);
    o.y = __float2bfloat16(v.y * inv);
    *((__hip_bfloat162*)(Xb + (size_t)row * DIM) + lane) = o;
    if (lane == 0) { pos[row] = 0.f; den[row] = 0.f; }
}

// ---- Kernel 2: fused gram + exp + row sums ----
// Block (rb, cg): rows [rb*128,+128) x 64-col tiles ct = cg*8..cg*8+7.
// 4 waves (wm=wave>>1 row-64-strip, wn=wave&1 col-32-strip); wave-tile 64x32
// via 4x2 MFMA 16x16x32 bf16 -> acc only 32 VGPRs, so 4 waves/SIMD fit.
// A fragments register-resident (64 VGPRs, loaded once from L2). B tiles
// (64 cols x 128 K = 16 KB) double-buffered in LDS via async global_load_lds;
// XOR swizzle folded into global source addresses keeps ds_read_b128
// fragment reads bank-conflict-free (verified structure from round 3).
// 1024 blocks -> 4 blocks/CU, 16 waves/CU: cross-block overlap hides the
// staging drain and barrier stalls.
__global__ __launch_bounds__(256, 4) void gram_kernel(
        const __hip_bfloat16* __restrict__ Xb,
        float* __restrict__ pos, float* __restrict__ den) {
    __shared__ __hip_bfloat16 Bs[2][64 * DIM];   // 2 x 16 KB
    const int tid  = threadIdx.x;
    const int rb   = blockIdx.x;      // 0..63   rows [rb*128, +128)
    const int cg   = blockIdx.y;      // 0..15   cols [cg*512, +512)
    const int lane = tid & 63;
    const int wave = tid >> 6;
    const int wm   = wave >> 1, wn = wave & 1;
    const int quad = lane >> 4;       // 0..3
    const int l15  = lane & 15;       // 0..15

    // A fragments: rows rb*128+wm*64+mi*16+l15, elems ko*32+quad*8 (one-time).
    short8 af[4][4];
    {
        const __hip_bfloat16* Ab = Xb + ((size_t)(rb * 128 + wm * 64 + l15)) * DIM + quad * 8;
        #pragma unroll
        for (int mi = 0; mi < 4; ++mi)
            #pragma unroll
            for (int ko = 0; ko < 4; ++ko)
                af[mi][ko] = *(const short8*)(Ab + mi * 16 * DIM + ko * 32);
    }

    float dp[4][4];
    #pragma unroll
    for (int a = 0; a < 4; ++a)
        #pragma unroll
        for (int b = 0; b < 4; ++b) dp[a][b] = 0.f;

    // Stage 64-col tile ct into Bs[buf]: 1024 16B-chunks, 4 issues/wave.
    // LDS chunk j holds global chunk (j&15)^(c&15) of col-row c = j>>4.
    auto stage = [&](int ct, int buf) {
        #pragma unroll
        for (int i = 0; i < 4; ++i) {
            int chunk = (i * 4 + wave) * 64 + lane;   // 0..1023
            int c  = chunk >> 4;                       // 0..63
            int cs = (chunk & 15) ^ (c & 15);
            const __hip_bfloat16* gp = Xb + ((size_t)(ct * 64 + c)) * DIM + cs * 8;
            char* lp = (char*)&Bs[buf][0] + (i * 4 + wave) * 1024;  // wave-uniform
            GLOAD_LDS(gp, lp);
        }
    };

    auto compute = [&](int ct, int buf) {
        floatx4 acc[4][2];
        #pragma unroll
        for (int mi = 0; mi < 4; ++mi)
            #pragma unroll
            for (int nl = 0; nl < 2; ++nl) acc[mi][nl] = (floatx4)0.0f;

        const char* Bb = (const char*)&Bs[buf][0];
        #pragma unroll
        for (int ko = 0; ko < 4; ++ko) {
            short8 bf[2];
            #pragma unroll
            for (int nl = 0; nl < 2; ++nl) {
                int c  = wn * 32 + nl * 16 + l15;     // c & 15 == l15
                int ch = (ko * 4 + quad) ^ l15;       // undo staging swizzle
                bf[nl] = *(const short8*)(Bb + c * 256 + ch * 16);
            }
            #pragma unroll
            for (int mi = 0; mi < 4; ++mi)
                #pragma unroll
                for (int nl = 0; nl < 2; ++nl)
                    acc[mi][nl] = __builtin_amdgcn_mfma_f32_16x16x32_bf16(
                        af[mi][ko], bf[nl], acc[mi][nl], 0, 0, 0);
        }

        // pos tile: this wave's 64 rows' positive block is 64-col tile rb*2+wm;
        // both wn halves contribute. Wave-uniform predicate.
        const bool pos_tile = (ct == rb * 2 + wm);
        #pragma unroll
        for (int mi = 0; mi < 4; ++mi)
            #pragma unroll
            for (int rg = 0; rg < 4; ++rg) {
                float dadd = EXP2F(acc[mi][0][rg]) + EXP2F(acc[mi][1][rg]);
                if (pos_tile) {
                    // diagonal element lives at ni == mi-wn*2, col l15 == quad*4+rg;
                    // replace bf16-noisy exp(10*||x||^2) with exact exp(10).
                    if ((mi >> 1) == wn && l15 == quad * 4 + rg)
                        dadd += EXPTEN - EXP2F(acc[mi][mi & 1][rg]);
                    float p = dadd;
                    #pragma unroll
                    for (int m = 1; m < 16; m <<= 1) p += __shfl_xor(p, m);
                    if (l15 == 0)
                        atomicAdd(&pos[rb * 128 + wm * 64 + mi * 16 + quad * 4 + rg], p);
                }
                dp[mi][rg] += dadd;
            }
    };

    const int ctBase = cg * CPS;
    stage(ctBase, 0);
    __syncthreads();                       // drains stage(0) + A loads
    #pragma unroll 1
    for (int t = 0; t < CPS - 1; ++t) {
        stage(ctBase + t + 1, (t + 1) & 1);  // async; drains at loop-end barrier
        compute(ctBase + t, t & 1);          // covers the staging latency
        __syncthreads();
    }
    compute(ctBase + CPS - 1, (CPS - 1) & 1);

    // den: reduce across the 16 lanes of each quad group, one atomic per row.
    #pragma unroll
    for (int mi = 0; mi < 4; ++mi)
        #pragma unroll
        for (int rg = 0; rg < 4; ++rg) {
            float d = dp[mi][rg];
            #pragma unroll
            for (int m = 1; m < 16; m <<= 1) d += __shfl_xor(d, m);
            if (l15 == 0)
                atomicAdd(&den[rb * 128 + wm * 64 + mi * 16 + quad * 4 + rg], d);
        }
}

// ---- Kernel 3: loss = mean(log(den/pos)) ----
__global__ void loss_kernel(const float* __restrict__ pos, const float* __restrict__ den,
                            float* __restrict__ out) {
    __shared__ float red[4];
    float acc = 0.f;
    for (int i = threadIdx.x; i < N_ROWS / 4; i += 256) {
        float4 d = ((const float4*)den)[i];
        float4 p = ((const float4*)pos)[i];
        acc += __logf(d.x / p.x) + __logf(d.y / p.y) +
               __logf(d.z / p.z) + __logf(d.w / p.w);
    }
    #pragma unroll
    for (int m = 1; m < 64; m <<= 1) acc += __shfl_xor(acc, m);
    int lane = threadIdx.x & 63, w = threadIdx.x >> 6;
    if (lane == 0) red[w] = acc;
    __syncthreads();
    if (threadIdx.x == 0)
        out[0] = (red[0] + red[1] + red[2] + red[3]) * (1.0f / (float)N_ROWS);
}

extern "C" void kernel_launch(void* const* d_in, const int* in_sizes, int n_in,
                              void* d_out, int out_size, void* d_ws, size_t ws_size,
                              hipStream_t stream) {
    const float* feature = (const float*)d_in[0];
    // ws layout: pos[8192] f32 | den[8192] f32 | Xb[8192*128] bf16
    float* pos = (float*)d_ws;
    float* den = pos + N_ROWS;
    __hip_bfloat16* Xb = (__hip_bfloat16*)(den + N_ROWS);

    norm_kernel<<<N_ROWS / 4, 256, 0, stream>>>(feature, Xb, pos, den);
    gram_kernel<<<dim3(64, 16), 256, 0, stream>>>(Xb, pos, den);
    loss_kernel<<<1, 256, 0, stream>>>(pos, den, (float*)d_out);
}

// Round 5
// 98.100 us; speedup vs baseline: 1.3065x; 1.3065x over previous
//
#include <hip/hip_runtime.h>
#include <hip/hip_bf16.h>

// feature [B=128, E=64, D=128] fp32 -> N = 8192 rows of dim 128.
// loss = mean_r( log(den_r) - log(pos_r) ),
//   den_r = sum_c exp(10*<f_r,f_c>), pos_r = sum over c in r's 64-row block.
#define N_ROWS 8192
#define DIM    128
#define EXPTEN 22026.465794806718f  // exp(10.0)
// Xb = normalize(f) * SCALE, SCALE^2 = 10*log2(e); then exp2(dot) = exp(10*<f,f>)
#define SCALE  3.7982826f

typedef __attribute__((ext_vector_type(8))) short short8;   // 8 bf16 = 4 VGPRs
typedef __attribute__((ext_vector_type(4))) float floatx4;  // MFMA C/D

#define EXP2F(x) __builtin_amdgcn_exp2f(x)

// async global->LDS DMA, 16B per lane; LDS dest = wave-uniform base + lane*16
#define GLOAD_LDS(g, l)                                                        \
    __builtin_amdgcn_global_load_lds(                                          \
        (const __attribute__((address_space(1))) void*)(g),                    \
        (__attribute__((address_space(3))) void*)(l), 16, 0, 0)

// ---- Kernel 1: L2-normalize rows, scale, cast to bf16; zero pos/den ----
__global__ void norm_kernel(const float* __restrict__ F, __hip_bfloat16* __restrict__ Xb,
                            float* __restrict__ pos, float* __restrict__ den) {
    int lane = threadIdx.x & 63;
    int wave = threadIdx.x >> 6;
    int row  = blockIdx.x * 4 + wave;           // 2048 blocks x 4 waves = 8192 rows
    const float2 v = *(const float2*)(F + (size_t)row * DIM + lane * 2);
    float ss = v.x * v.x + v.y * v.y;
    #pragma unroll
    for (int m = 1; m < 64; m <<= 1) ss += __shfl_xor(ss, m);
    float inv = rsqrtf(ss) * SCALE;
    __hip_bfloat162 o;
    o.x = __float2bfloat16(v.x * inv);
    o.y = __float2bfloat16(v.y * inv);
    *((__hip_bfloat162*)(Xb + (size_t)row * DIM) + lane) = o;
    if (lane == 0) { pos[row] = 0.f; den[row] = 0.f; }
}

// ---- Kernel 2: fused gram + exp + row sums ----
// Block (rb, cg): rows [rb*128,+128) x a run of 64-col tiles (10 or 11 tiles;
// the 128 tiles are split 4x10 + 8x11 over 12 groups -> 64x12 = 768 blocks
// = exactly 3 blocks/CU, no residency tail).
// 4 waves (wm row-64-strip, wn col-32-strip); wave-tile 64x32 via 4x2 MFMA
// 16x16x32 bf16 -> acc 32 VGPRs. A fragments register-resident (64 VGPRs).
// B tiles (64 cols x 128 K = 16 KB) double-buffered in LDS via async
// global_load_lds; XOR swizzle folded into global source addresses keeps the
// ds_read_b128 fragment reads bank-conflict-free (0 conflicts measured).
// launch_bounds(256,3): VGPR cap 170 > ~140 needed -> NO SPILL (round 4's
// (256,4) cap of 128 spilled 64 regs -> 67 MB scratch writes, 2x regression).
__global__ __launch_bounds__(256, 3) void gram_kernel(
        const __hip_bfloat16* __restrict__ Xb,
        float* __restrict__ pos, float* __restrict__ den) {
    __shared__ __hip_bfloat16 Bs[2][64 * DIM];   // 2 x 16 KB
    const int tid  = threadIdx.x;
    const int rb   = blockIdx.x;      // 0..63   rows [rb*128, +128)
    const int cg   = blockIdx.y;      // 0..11   col-tile group
    const int lane = tid & 63;
    const int wave = tid >> 6;
    const int wm   = wave >> 1, wn = wave & 1;
    const int quad = lane >> 4;       // 0..3
    const int l15  = lane & 15;       // 0..15

    // col-tile partition: groups 0..3 get 10 tiles, 4..11 get 11 (4*10+8*11=128)
    const int start = (cg < 4) ? cg * 10 : 40 + (cg - 4) * 11;
    const int cnt   = (cg < 4) ? 10 : 11;

    // A fragments: rows rb*128+wm*64+mi*16+l15, elems ko*32+quad*8 (one-time).
    short8 af[4][4];
    {
        const __hip_bfloat16* Ab = Xb + ((size_t)(rb * 128 + wm * 64 + l15)) * DIM + quad * 8;
        #pragma unroll
        for (int mi = 0; mi < 4; ++mi)
            #pragma unroll
            for (int ko = 0; ko < 4; ++ko)
                af[mi][ko] = *(const short8*)(Ab + mi * 16 * DIM + ko * 32);
    }

    float dp[4][4];
    #pragma unroll
    for (int a = 0; a < 4; ++a)
        #pragma unroll
        for (int b = 0; b < 4; ++b) dp[a][b] = 0.f;

    // Stage 64-col tile ct into Bs[buf]: 1024 16B-chunks, 4 issues/wave.
    // LDS chunk j holds global chunk (j&15)^(c&15) of col-row c = j>>4.
    auto stage = [&](int ct, int buf) {
        #pragma unroll
        for (int i = 0; i < 4; ++i) {
            int chunk = (i * 4 + wave) * 64 + lane;   // 0..1023
            int c  = chunk >> 4;                       // 0..63
            int cs = (chunk & 15) ^ (c & 15);
            const __hip_bfloat16* gp = Xb + ((size_t)(ct * 64 + c)) * DIM + cs * 8;
            char* lp = (char*)&Bs[buf][0] + (i * 4 + wave) * 1024;  // wave-uniform
            GLOAD_LDS(gp, lp);
        }
    };

    auto compute = [&](int ct, int buf) {
        floatx4 acc[4][2];
        #pragma unroll
        for (int mi = 0; mi < 4; ++mi)
            #pragma unroll
            for (int nl = 0; nl < 2; ++nl) acc[mi][nl] = (floatx4)0.0f;

        const char* Bb = (const char*)&Bs[buf][0];
        #pragma unroll
        for (int ko = 0; ko < 4; ++ko) {
            short8 bf[2];
            #pragma unroll
            for (int nl = 0; nl < 2; ++nl) {
                int c  = wn * 32 + nl * 16 + l15;     // c & 15 == l15
                int ch = (ko * 4 + quad) ^ l15;       // undo staging swizzle
                bf[nl] = *(const short8*)(Bb + c * 256 + ch * 16);
            }
            #pragma unroll
            for (int mi = 0; mi < 4; ++mi)
                #pragma unroll
                for (int nl = 0; nl < 2; ++nl)
                    acc[mi][nl] = __builtin_amdgcn_mfma_f32_16x16x32_bf16(
                        af[mi][ko], bf[nl], acc[mi][nl], 0, 0, 0);
        }

        // pos tile: this wave's 64 rows' positive block is 64-col tile rb*2+wm;
        // both wn halves contribute. Wave-uniform predicate.
        const bool pos_tile = (ct == rb * 2 + wm);
        #pragma unroll
        for (int mi = 0; mi < 4; ++mi)
            #pragma unroll
            for (int rg = 0; rg < 4; ++rg) {
                float dadd = EXP2F(acc[mi][0][rg]) + EXP2F(acc[mi][1][rg]);
                if (pos_tile) {
                    // diagonal element lives at nl == mi&1 when mi>>1 == wn,
                    // col l15 == quad*4+rg; replace bf16-noisy exp(10*||x||^2)
                    // with exact exp(10).
                    if ((mi >> 1) == wn && l15 == quad * 4 + rg)
                        dadd += EXPTEN - EXP2F(acc[mi][mi & 1][rg]);
                    float p = dadd;
                    #pragma unroll
                    for (int m = 1; m < 16; m <<= 1) p += __shfl_xor(p, m);
                    if (l15 == 0)
                        atomicAdd(&pos[rb * 128 + wm * 64 + mi * 16 + quad * 4 + rg], p);
                }
                dp[mi][rg] += dadd;
            }
    };

    stage(start, 0);
    __syncthreads();                       // drains stage(0) + A loads
    #pragma unroll 1
    for (int t = 0; t < cnt - 1; ++t) {
        stage(start + t + 1, (t + 1) & 1);  // async; drains at loop-end barrier
        compute(start + t, t & 1);          // covers the staging latency
        __syncthreads();
    }
    compute(start + cnt - 1, (cnt - 1) & 1);

    // den: reduce across the 16 lanes of each quad group, one atomic per row.
    #pragma unroll
    for (int mi = 0; mi < 4; ++mi)
        #pragma unroll
        for (int rg = 0; rg < 4; ++rg) {
            float d = dp[mi][rg];
            #pragma unroll
            for (int m = 1; m < 16; m <<= 1) d += __shfl_xor(d, m);
            if (l15 == 0)
                atomicAdd(&den[rb * 128 + wm * 64 + mi * 16 + quad * 4 + rg], d);
        }
}

// ---- Kernel 3: loss = mean(log(den/pos)) ----
__global__ void loss_kernel(const float* __restrict__ pos, const float* __restrict__ den,
                            float* __restrict__ out) {
    __shared__ float red[4];
    float acc = 0.f;
    for (int i = threadIdx.x; i < N_ROWS / 4; i += 256) {
        float4 d = ((const float4*)den)[i];
        float4 p = ((const float4*)pos)[i];
        acc += __logf(d.x / p.x) + __logf(d.y / p.y) +
               __logf(d.z / p.z) + __logf(d.w / p.w);
    }
    #pragma unroll
    for (int m = 1; m < 64; m <<= 1) acc += __shfl_xor(acc, m);
    int lane = threadIdx.x & 63, w = threadIdx.x >> 6;
    if (lane == 0) red[w] = acc;
    __syncthreads();
    if (threadIdx.x == 0)
        out[0] = (red[0] + red[1] + red[2] + red[3]) * (1.0f / (float)N_ROWS);
}

extern "C" void kernel_launch(void* const* d_in, const int* in_sizes, int n_in,
                              void* d_out, int out_size, void* d_ws, size_t ws_size,
                              hipStream_t stream) {
    const float* feature = (const float*)d_in[0];
    // ws layout: pos[8192] f32 | den[8192] f32 | Xb[8192*128] bf16
    float* pos = (float*)d_ws;
    float* den = pos + N_ROWS;
    __hip_bfloat16* Xb = (__hip_bfloat16*)(den + N_ROWS);

    norm_kernel<<<N_ROWS / 4, 256, 0, stream>>>(feature, Xb, pos, den);
    gram_kernel<<<dim3(64, 12), 256, 0, stream>>>(Xb, pos, den);
    loss_kernel<<<1, 256, 0, stream>>>(pos, den, (float*)d_out);
}